// Round 10
// baseline (139.823 us; speedup 1.0000x reference)
//
#include <hip/hip_runtime.h>
#include <math.h>

#define Dm   768
#define Hm   64
#define SEQ  4096
#define NB   4
#define NROW (NB * SEQ)

// scale 1/sqrt(64) and log2(e) folded into Wq at wconv time -> exp2 domain
#define QSCALE (0.125f * 1.4426950408889634f)

typedef _Float16 f16;
typedef __attribute__((ext_vector_type(8))) _Float16 f16x8;
typedef __attribute__((ext_vector_type(2))) __fp16 fp16x2_raw;
typedef __attribute__((ext_vector_type(4))) float f32x4;
typedef unsigned int uint;
typedef unsigned short ushort;

#define MFMAH(A, B, C) __builtin_amdgcn_mfma_f32_16x16x32_f16(A, B, C, 0, 0, 0)

__device__ __forceinline__ uint pkrtz(float a, float b) {
    fp16x2_raw r = __builtin_amdgcn_cvt_pkrtz(a, b);
    return __builtin_bit_cast(uint, r);
}
__device__ __forceinline__ ushort f2h(float f) {
    f16 h = (f16)f;
    return __builtin_bit_cast(ushort, h);
}
union F16x8U { uint u[4]; f16x8 v; };

// ---------------------------------------------------------------------------
// Kernel 0: W -> WTt f16, tiled [kt(24)][c(192)][kk(32)].  (unchanged)
// ---------------------------------------------------------------------------
__global__ __launch_bounds__(256) void wconv(
    const float* __restrict__ Wq, const float* __restrict__ Wk,
    const float* __restrict__ Wv, ushort* __restrict__ WTt)
{
    const int c   = blockIdx.x;
    const int mat = c >> 6, col = c & 63;
    const float* W = (mat == 0) ? Wq : (mat == 1 ? Wk : Wv);
    const float sc = (mat == 0) ? QSCALE : 1.0f;
    for (int k = threadIdx.x; k < Dm; k += 256)
        WTt[((size_t)(k >> 5) * 192 + c) * 32 + (k & 31)] = f2h(W[k * 64 + col] * sc);
}

// ---------------------------------------------------------------------------
// Kernel 1: f16 MFMA QKV projection, split-K=4.  (unchanged from R9)
// ---------------------------------------------------------------------------
__global__ __launch_bounds__(256, 3) void proj(
    const float* __restrict__ ix, const ushort* __restrict__ WTt,
    ushort* __restrict__ Qw, ushort* __restrict__ Kt, ushort* __restrict__ Vt)
{
    __shared__ __align__(16) float comb[2][3072];   // 24 KiB

    const int t    = threadIdx.x;
    const int lane = t & 63;
    const int kh   = __builtin_amdgcn_readfirstlane(t >> 6);
    const int q15  = lane & 15, quad = lane >> 4;
    const int gr0  = blockIdx.x * 16;

    const float*  Ab = ix + (size_t)(gr0 + q15) * Dm + kh * 192 + quad * 8;
    const ushort* Bb = WTt + ((size_t)(kh * 6) * 192 + q15) * 32 + quad * 8;

    f32x4 acc[12];
#pragma unroll
    for (int ct = 0; ct < 12; ++ct) acc[ct] = (f32x4){0.f, 0.f, 0.f, 0.f};

    f32x4 Af[3][2];   // ring-3, distance-2
#pragma unroll
    for (int i = 0; i < 2; ++i) {
        Af[i][0] = *(const f32x4*)(Ab + i * 32);
        Af[i][1] = *(const f32x4*)(Ab + i * 32 + 4);
    }

#pragma unroll
    for (int it = 0; it < 6; ++it) {
        f16x8 Bf[12];
#pragma unroll
        for (int ct = 0; ct < 12; ++ct)
            Bf[ct] = *(const f16x8*)(Bb + (size_t)it * 6144 + ct * 512);

        if (it + 2 < 6) {
            Af[(it + 2) % 3][0] = *(const f32x4*)(Ab + (it + 2) * 32);
            Af[(it + 2) % 3][1] = *(const f32x4*)(Ab + (it + 2) * 32 + 4);
        }

        F16x8U af;
        af.u[0] = pkrtz(Af[it % 3][0].x, Af[it % 3][0].y);
        af.u[1] = pkrtz(Af[it % 3][0].z, Af[it % 3][0].w);
        af.u[2] = pkrtz(Af[it % 3][1].x, Af[it % 3][1].y);
        af.u[3] = pkrtz(Af[it % 3][1].z, Af[it % 3][1].w);
#pragma unroll
        for (int ct = 0; ct < 12; ++ct)
            acc[ct] = MFMAH(af.v, Bf[ct], acc[ct]);
    }

    if (kh >= 2) {
#pragma unroll
        for (int ct = 0; ct < 12; ++ct)
            *(f32x4*)&comb[kh - 2][(ct * 64 + lane) * 4] = acc[ct];
    }
    __syncthreads();
    if (kh < 2) {
#pragma unroll
        for (int ct = 0; ct < 12; ++ct) {
            f32x4 o = *(const f32x4*)&comb[kh][(ct * 64 + lane) * 4];
            acc[ct].x += o.x; acc[ct].y += o.y; acc[ct].z += o.z; acc[ct].w += o.w;
        }
    }
    __syncthreads();
    if (kh == 1) {
#pragma unroll
        for (int ct = 0; ct < 12; ++ct)
            *(f32x4*)&comb[0][(ct * 64 + lane) * 4] = acc[ct];
    }
    __syncthreads();
    if (kh == 0) {
#pragma unroll
        for (int ct = 0; ct < 12; ++ct) {
            f32x4 o = *(const f32x4*)&comb[0][(ct * 64 + lane) * 4];
            acc[ct].x += o.x; acc[ct].y += o.y; acc[ct].z += o.z; acc[ct].w += o.w;
        }
        const int h16 = (gr0 >> 4) & 1;
        const int n4  = gr0 >> 4;
        const int j32 = gr0 >> 5;
#pragma unroll
        for (int ct = 0; ct < 12; ++ct) {
            float vals[4] = {acc[ct].x, acc[ct].y, acc[ct].z, acc[ct].w};
            if (ct < 4) {
#pragma unroll
                for (int r = 0; r < 4; ++r)
                    Qw[(size_t)(gr0 + quad * 4 + r) * 64 + ct * 16 + q15] = f2h(vals[r]);
            } else if (ct < 8) {
#pragma unroll
                for (int r = 0; r < 4; ++r)
                    Kt[(size_t)n4 * 1024 + (ct - 4) * 256 + (quad * 4 + r) * 16 + q15] = f2h(vals[r]);
            } else {
                ushort4 vv;
                vv.x = f2h(vals[0]); vv.y = f2h(vals[1]);
                vv.z = f2h(vals[2]); vv.w = f2h(vals[3]);
                *(ushort4*)(Vt + (size_t)j32 * 2048 + (ct - 8) * 512 +
                            (h16 * 2 + (quad >> 1)) * 128 + q15 * 8 + (quad & 1) * 4) = vv;
            }
        }
    }
}

// ---------------------------------------------------------------------------
// Kernel 2a: attention pass 1, j-split x2 across blocks. grid 1024 x 256
// (3 blocks/CU via LB(256,3): ~160 VGPR -> 3 waves/SIMD, vs 2 before).
// bb: xcd=bb&7 -> batch=xcd>>1, half=xcd&1; slot=bb>>3 (0..127); 32 q/block.
// Wave w owns j in [half*2048 + w*512, +512) = 16 iters of 32 keys.
// K ring-3 distance-2, V ring-2 distance-1, PV lag-1 with P-dbuf in LDS.
// Partial o (f32) and l written to ws; no-max softmax => combine is a sum.
// ---------------------------------------------------------------------------
__global__ __launch_bounds__(256, 3) void attn_p1(
    const ushort* __restrict__ Qw, const ushort* __restrict__ Kt,
    const ushort* __restrict__ Vt, float* __restrict__ po, float* __restrict__ pl)
{
    // floats [0,4096): two combine bufs, aliased by P strips during the loop
    // (shorts [0,10240) = 4 waves x 2 bufs x 32q x 40). floats [5120,5248): l.
    __shared__ __align__(16) float aF[5248];   // 20992 B
    short* aS = (short*)aF;

    const int t    = threadIdx.x;
    const int lane = t & 63;
    const int w    = __builtin_amdgcn_readfirstlane(t >> 6);
    const int q15  = lane & 15, quad = lane >> 4;

    const int bb    = blockIdx.x;
    const int xcd   = bb & 7;
    const int batch = xcd >> 1;
    const int half  = xcd & 1;
    const int slot  = bb >> 3;           // 0..127
    const int q0    = slot * 32;
    const size_t base = (size_t)batch * SEQ;

    f16x8 qf[2][2];
#pragma unroll
    for (int g = 0; g < 2; ++g)
#pragma unroll
        for (int h = 0; h < 2; ++h)
            qf[g][h] = *(const f16x8*)(Qw + (base + q0 + g * 16 + q15) * 64 + h * 32 + quad * 8);

    f32x4 oacc[2][4];
#pragma unroll
    for (int g = 0; g < 2; ++g)
#pragma unroll
        for (int dt = 0; dt < 4; ++dt) oacc[g][dt] = (f32x4){0.f, 0.f, 0.f, 0.f};
    float lsum[2] = {0.f, 0.f};

    const size_t j0g = base + half * 2048 + w * 512;
    const ushort* Kfb = Kt + (j0g >> 4) * 1024;
    const ushort* Vfb = Vt + (j0g >> 5) * 2048 + lane * 8;
    short* Ps = aS + w * 2560;           // 2 bufs x [32 q][40]

    int koff[2][2];
#pragma unroll
    for (int jt = 0; jt < 2; ++jt)
#pragma unroll
        for (int h = 0; h < 2; ++h)
            koff[jt][h] = jt * 1024 + h * 512 + (quad >> 1) * 256 + q15 * 16 + (quad & 1) * 8;

    f16x8 kf[3][2][2];   // ring-3, distance-2
    f16x8 vf[2][4];      // ring-2, distance-1

#define LOADK(s, i)                                                            \
    {                                                                          \
        _Pragma("unroll") for (int jt = 0; jt < 2; ++jt)                       \
        _Pragma("unroll") for (int h = 0; h < 2; ++h)                          \
            kf[s][jt][h] = *(const f16x8*)(Kfb + (size_t)(i) * 2048 + koff[jt][h]); \
    }
#define LOADV(s, i)                                                            \
    {                                                                          \
        _Pragma("unroll") for (int dt = 0; dt < 4; ++dt)                       \
            vf[s][dt] = *(const f16x8*)(Vfb + (size_t)(i) * 2048 + dt * 512);  \
    }
#define QKSTEP(s, pb)                                                          \
    {                                                                          \
        _Pragma("unroll") for (int g = 0; g < 2; ++g)                          \
        _Pragma("unroll") for (int jt = 0; jt < 2; ++jt) {                     \
            f32x4 z = (f32x4){0.f, 0.f, 0.f, 0.f};                             \
            z = MFMAH(kf[s][jt][0], qf[g][0], z);                              \
            z = MFMAH(kf[s][jt][1], qf[g][1], z);                              \
            float e0 = exp2f(z.x), e1 = exp2f(z.y);                            \
            float e2 = exp2f(z.z), e3 = exp2f(z.w);                            \
            lsum[g] += (e0 + e1) + (e2 + e3);                                  \
            uint2 pk = make_uint2(pkrtz(e0, e1), pkrtz(e2, e3));               \
            *(uint2*)(Ps + (pb) * 1280 + (g * 16 + q15) * 40 + jt * 16 + quad * 4) = pk; \
        }                                                                      \
    }
#define PVSTEP(s, pb)                                                          \
    {                                                                          \
        f16x8 pf[2];                                                           \
        _Pragma("unroll") for (int g = 0; g < 2; ++g)                          \
            pf[g] = *(const f16x8*)(Ps + (pb) * 1280 + (g * 16 + q15) * 40 + quad * 8); \
        _Pragma("unroll") for (int dt = 0; dt < 4; ++dt)                       \
        _Pragma("unroll") for (int g = 0; g < 2; ++g)                          \
            oacc[g][dt] = MFMAH(pf[g], vf[s][dt], oacc[g][dt]);                \
    }

    LOADK(0, 0);
    LOADV(0, 0);
    LOADK(1, 1);
    QKSTEP(0, 0);
#pragma unroll
    for (int i = 0; i < 16; ++i) {
        if (i + 2 < 16) LOADK((i + 2) % 3, i + 2);
        if (i + 1 < 16) LOADV((i + 1) & 1, i + 1);   // WAR-safe: PV reads i&1
        if (i + 1 < 16) QKSTEP((i + 1) % 3, (i + 1) & 1);
        PVSTEP(i & 1, i & 1);
    }

    // ---- l: quad-reduce, publish per wave (P strips dead after loop) ----
#pragma unroll
    for (int g = 0; g < 2; ++g) {
        lsum[g] += __shfl_xor(lsum[g], 16);
        lsum[g] += __shfl_xor(lsum[g], 32);
    }
    if (quad == 0) {
#pragma unroll
        for (int g = 0; g < 2; ++g)
            aF[5120 + w * 32 + g * 16 + q15] = lsum[g];
    }
    __syncthreads();

    // ---- 4-way tree combine of o through LDS ----
#define OWRITE(idx)                                                          \
    {                                                                        \
        float* b = aF + (idx) * 2048;                                        \
        _Pragma("unroll") for (int g = 0; g < 2; ++g)                        \
        _Pragma("unroll") for (int dt = 0; dt < 4; ++dt) {                   \
            b[(g * 16 + quad * 4 + 0) * 64 + dt * 16 + q15] = oacc[g][dt].x; \
            b[(g * 16 + quad * 4 + 1) * 64 + dt * 16 + q15] = oacc[g][dt].y; \
            b[(g * 16 + quad * 4 + 2) * 64 + dt * 16 + q15] = oacc[g][dt].z; \
            b[(g * 16 + quad * 4 + 3) * 64 + dt * 16 + q15] = oacc[g][dt].w; \
        }                                                                    \
    }
#define OADD(idx)                                                            \
    {                                                                        \
        const float* b = aF + (idx) * 2048;                                  \
        _Pragma("unroll") for (int g = 0; g < 2; ++g)                        \
        _Pragma("unroll") for (int dt = 0; dt < 4; ++dt) {                   \
            oacc[g][dt].x += b[(g * 16 + quad * 4 + 0) * 64 + dt * 16 + q15];\
            oacc[g][dt].y += b[(g * 16 + quad * 4 + 1) * 64 + dt * 16 + q15];\
            oacc[g][dt].z += b[(g * 16 + quad * 4 + 2) * 64 + dt * 16 + q15];\
            oacc[g][dt].w += b[(g * 16 + quad * 4 + 3) * 64 + dt * 16 + q15];\
        }                                                                    \
    }
    if (w >= 2) OWRITE(w - 2);
    __syncthreads();
    if (w < 2) OADD(w);
    __syncthreads();
    if (w == 1) OWRITE(0);
    __syncthreads();
    if (w == 0) {
        OADD(0);
        // partial o store: [bb][32 q][64 d] f32
        float* pob = po + (size_t)bb * 2048;
#pragma unroll
        for (int g = 0; g < 2; ++g)
#pragma unroll
            for (int dt = 0; dt < 4; ++dt) {
                pob[(g * 16 + quad * 4 + 0) * 64 + dt * 16 + q15] = oacc[g][dt].x;
                pob[(g * 16 + quad * 4 + 1) * 64 + dt * 16 + q15] = oacc[g][dt].y;
                pob[(g * 16 + quad * 4 + 2) * 64 + dt * 16 + q15] = oacc[g][dt].z;
                pob[(g * 16 + quad * 4 + 3) * 64 + dt * 16 + q15] = oacc[g][dt].w;
            }
        if (quad == 0) {
#pragma unroll
            for (int g = 0; g < 2; ++g) {
                int qq = g * 16 + q15;
                float lt = aF[5120 + qq] + aF[5120 + 32 + qq] +
                           aF[5120 + 64 + qq] + aF[5120 + 96 + qq];
                pl[(size_t)bb * 32 + qq] = lt;
            }
        }
    }
}

// ---------------------------------------------------------------------------
// Kernel 2b: fixup -- out = (o0 + o1) / (l0 + l1).  grid 512 x 256.
// ---------------------------------------------------------------------------
__global__ __launch_bounds__(256) void fixup(
    const float* __restrict__ po, const float* __restrict__ pl,
    float* __restrict__ out)
{
    const int g  = blockIdx.x * 256 + threadIdx.x;   // 131072 threads
    const int n  = g >> 3;                           // row 0..16383
    const int d0 = (g & 7) * 8;
    const int batch = n >> 12;
    const int slot  = (n & 4095) >> 5;
    const int q     = n & 31;
    const int bb0 = (slot << 3) | (batch << 1);      // half 0
    const int bb1 = bb0 | 1;                         // half 1

    const float linv = 1.0f / (pl[(size_t)bb0 * 32 + q] + pl[(size_t)bb1 * 32 + q]);
    const float* p0 = po + (size_t)bb0 * 2048 + q * 64 + d0;
    const float* p1 = po + (size_t)bb1 * 2048 + q * 64 + d0;
#pragma unroll
    for (int k2 = 0; k2 < 2; ++k2) {
        float4 a = *(const float4*)(p0 + k2 * 4);
        float4 b = *(const float4*)(p1 + k2 * 4);
        float4 s;
        s.x = (a.x + b.x) * linv; s.y = (a.y + b.y) * linv;
        s.z = (a.z + b.z) * linv; s.w = (a.w + b.w) * linv;
        *(float4*)(out + (size_t)n * 64 + d0 + k2 * 4) = s;
    }
}

// ---------------------------------------------------------------------------
extern "C" void kernel_launch(void* const* d_in, const int* in_sizes, int n_in,
                              void* d_out, int out_size, void* d_ws, size_t ws_size,
                              hipStream_t stream)
{
    const float* ix = (const float*)d_in[0];
    const float* Wk = (const float*)d_in[1];
    const float* Wq = (const float*)d_in[2];
    const float* Wv = (const float*)d_in[3];
    float* out = (float*)d_out;

    // ws: Qw | Kt | Vt (2 MB each) | WTt (0.6 MB) | po (8.4 MB) | pl (132 KB)
    ushort* Qw  = (ushort*)d_ws;
    ushort* Kt  = Qw + (size_t)NROW * Hm;
    ushort* Vt  = Kt + (size_t)NROW * Hm;
    ushort* WTt = Vt + (size_t)NROW * Hm;
    float*  po  = (float*)(WTt + (size_t)24 * 192 * 32);
    float*  pl  = po + (size_t)1024 * 2048;

    wconv<<<192, 256, 0, stream>>>(Wq, Wk, Wv, WTt);
    proj<<<1024, 256, 0, stream>>>(ix, WTt, Qw, Kt, Vt);
    attn_p1<<<1024, 256, 0, stream>>>(Qw, Kt, Vt, po, pl);
    fixup<<<512, 256, 0, stream>>>(po, pl, out);
}